// Round 2
// baseline (1081.470 us; speedup 1.0000x reference)
//
#include <hip/hip_runtime.h>
#include <stdint.h>

typedef _Float16 v8h __attribute__((ext_vector_type(8)));
typedef _Float16 v4h __attribute__((ext_vector_type(4)));
typedef float v4f __attribute__((ext_vector_type(4)));

#define GLL16(gp, lp) __builtin_amdgcn_global_load_lds( \
    (const __attribute__((address_space(1))) void*)(gp), \
    (__attribute__((address_space(3))) void*)(lp), 16, 0, 0)

// ---------------------------------------------------------------------------
// fp32 -> fp16 pack (8 elems/thread, coalesced)
// ---------------------------------------------------------------------------
__global__ __launch_bounds__(256) void cvt_f32_f16(
    const float* __restrict__ in, _Float16* __restrict__ out, size_t n)
{
    size_t i = ((size_t)blockIdx.x * 256 + threadIdx.x) * 8;
    if (i >= n) return;
    float4 a = *(const float4*)(in + i);
    float4 b = *(const float4*)(in + i + 4);
    v8h h;
    h[0] = (_Float16)a.x; h[1] = (_Float16)a.y;
    h[2] = (_Float16)a.z; h[3] = (_Float16)a.w;
    h[4] = (_Float16)b.x; h[5] = (_Float16)b.y;
    h[6] = (_Float16)b.z; h[7] = (_Float16)b.w;
    *(v8h*)(out + i) = h;
}

// ---------------------------------------------------------------------------
// 256x256-tile 8-wave GEMM, 4 phases per K-tile, TWO barriers per K-tile.
//   Y[m,n] = sum_k Xh[m,k]*Wh[n,k] + bias[n]
// LDS (128 KiB dynamic): buf[2] x { A: 2 halves, B: 2 halves } of 128x64 fp16.
// Swizzle: physical 16B slot p of row r holds logical slot p ^ (r&7)
//          (pre-swizzled global source feeding linear global_load_lds dest).
//
// Stage issue order (2 loads each):
//   ... B1(t)@ph4(t-2) | A1(t)@ph1(t-1) A0(t+1)@ph2(t-1) B0(t+1)@ph3(t-1)
//       B1(t+1)@ph4(t-1) | A1(t+1)@ph1(t) A0(t+2)@ph2(t) B0(t+2)@ph3(t) ...
// RAW:  vmcnt(8)@ph2(t)  leaves newest 4 stages -> A1(t) landed  (ph3 reads)
//       vmcnt(6)@ph4(t)  leaves newest 3 stages -> B1(t+1), B0(t+1), A0(t+1)
//                         landed (ph1/ph2 of t+1 read them)
// WAR:  every STAGE that overwrites a region is issued AFTER a barrier that
//       its last readers reached only after their lgkm-complete (reads feed
//       the MFMA preceding that barrier). Stages at ph2/ph4 sit after BAR.
// vmcnt never drains to 0; barriers only at ph2 and ph4.
// ---------------------------------------------------------------------------
__global__ __launch_bounds__(512, 2) void gemm_f16_256(
    const _Float16* __restrict__ Xh,  // [M,K] fp16
    const _Float16* __restrict__ Wh,  // [N,K] fp16
    const float* __restrict__ bias,
    float* __restrict__ Y,
    int M, int N, int K)
{
    extern __shared__ _Float16 lds[];   // 65536 fp16 = 128 KiB
    const int NT   = K >> 6;            // K-tiles of 64
    const int tid  = threadIdx.x;
    const int lane = tid & 63;
    const int w    = tid >> 6;          // wave 0..7
    const int wr   = w >> 2;            // 0..1 (M sub-rows)
    const int wc   = w & 3;             // 0..3 (N sub-cols)
    const int lq   = lane >> 4;         // 0..3
    const int lr   = lane & 15;         // 0..15
    const int l8   = lane >> 3;         // 0..7
    const int c8   = lane & 7;          // 0..7
    const int lx   = lr & 7;

    // XCD-aware bijective block swizzle (grid is a multiple of 8 here)
    const int nwg = (int)gridDim.x;
    int wg = (int)blockIdx.x;
    if ((nwg & 7) == 0) wg = (wg & 7) * (nwg >> 3) + (wg >> 3);
    const int ntx = N >> 8;
    const int bx = wg % ntx, by = wg / ntx;
    const int bm = by << 8, bn = bx << 8;

    // staging invariants: per call a wave fills 8 rows x 64 fp16 (1 KiB linear)
    const int rbase = (w << 3) + l8;          // 0..63
    const int scol  = (c8 ^ l8) << 3;         // pre-swizzled source column
    const _Float16* pA = Xh + (size_t)(bm + rbase) * K + scol;
    const _Float16* pB = Wh + (size_t)(bn + rbase) * K + scol;

#define STAGE(mat, h, tt) do { \
    const int ttc = ((tt) < NT) ? (tt) : (NT - 1); \
    const _Float16* gp_ = (mat) ? pB : pA; \
    const size_t go_ = (size_t)((h) * 128) * K + (size_t)ttc * 64; \
    _Float16* lp_ = lds + (((tt) & 1) << 15) + ((mat) << 14) + ((h) << 13) + (w << 9); \
    GLL16(gp_ + go_, lp_); \
    GLL16(gp_ + go_ + (size_t)64 * K, lp_ + 4096); } while (0)

#define LOAD_AF(h) do { \
    const _Float16* ab_ = lds + cbuf + ((h) << 13); \
    _Pragma("unroll") \
    for (int im = 0; im < 4; ++im) { \
      const int rr_ = wr * 64 + im * 16 + lr; \
      _Pragma("unroll") \
      for (int ks = 0; ks < 2; ++ks) \
        af[im][ks] = *(const v8h*)(ab_ + rr_ * 64 + (((ks * 4 + lq) ^ lx) << 3)); \
    } } while (0)

#define LOAD_BF(h, BF) do { \
    const _Float16* bb_ = lds + cbuf + 16384 + ((h) << 13); \
    _Pragma("unroll") \
    for (int in = 0; in < 2; ++in) { \
      const int rr_ = wc * 32 + in * 16 + lr; \
      _Pragma("unroll") \
      for (int ks = 0; ks < 2; ++ks) \
        BF[in][ks] = *(const v8h*)(bb_ + rr_ * 64 + (((ks * 4 + lq) ^ lx) << 3)); \
    } } while (0)

#define MFMA_Q(qa, qb, BF) do { \
    __builtin_amdgcn_s_setprio(1); \
    _Pragma("unroll") \
    for (int im = 0; im < 4; ++im) \
      _Pragma("unroll") \
      for (int in = 0; in < 2; ++in) \
        _Pragma("unroll") \
        for (int ks = 0; ks < 2; ++ks) \
          acc[qa][qb][im][in] = __builtin_amdgcn_mfma_f32_16x16x32_f16( \
              af[im][ks], BF[in][ks], acc[qa][qb][im][in], 0, 0, 0); \
    __builtin_amdgcn_s_setprio(0); } while (0)

    v4f acc[2][2][4][2];
    #pragma unroll
    for (int qa = 0; qa < 2; ++qa)
      #pragma unroll
      for (int qb = 0; qb < 2; ++qb)
        #pragma unroll
        for (int im = 0; im < 4; ++im)
          #pragma unroll
          for (int in = 0; in < 2; ++in)
            acc[qa][qb][im][in] = (v4f){0.f, 0.f, 0.f, 0.f};

    v8h af[4][2], bf0[2][2], bf1[2][2];

    // prologue: 7 stages; vmcnt(8) leaves newest 4 stages in flight and
    // guarantees A0(0), B0(0), B1(0) landed (ph1/ph2 of t=0 need them).
    STAGE(0, 0, 0); STAGE(1, 0, 0); STAGE(1, 1, 0); STAGE(0, 1, 0);
    STAGE(0, 0, 1); STAGE(1, 0, 1); STAGE(1, 1, 1);
    asm volatile("s_waitcnt vmcnt(8)" ::: "memory");
    __builtin_amdgcn_s_barrier();

    for (int t = 0; t < NT; ++t) {
        const int cbuf = (t & 1) << 15;

        // ---- phase 1 : Q(A0,B0) ----  (no barrier; overlaps prev MFMA tail)
        LOAD_AF(0);
        LOAD_BF(0, bf0);
        STAGE(0, 1, t + 1);            // A1(t+1) -> other buf (readers done
                                       // before BAR@ph4(t-1))
        MFMA_Q(0, 0, bf0);

        // ---- phase 2 : Q(A0,B1) ----
        LOAD_BF(1, bf1);               // B1(t): landed per vmcnt(6)@ph4(t-1)
        asm volatile("s_waitcnt vmcnt(8)" ::: "memory");  // A1(t) landed
        __builtin_amdgcn_s_barrier();
        STAGE(0, 0, t + 2);            // overwrites A0(t); readers done pre-BAR
        MFMA_Q(0, 1, bf1);

        // ---- phase 3 : Q(A1,B1) ----  (no barrier)
        LOAD_AF(1);
        STAGE(1, 0, t + 2);            // overwrites B0(t); BAR@ph2 separates
        MFMA_Q(1, 1, bf1);

        // ---- phase 4 : Q(A1,B0) ----
        asm volatile("s_waitcnt vmcnt(6)" ::: "memory");  // t+1's A0,B0,B1 landed
        __builtin_amdgcn_s_barrier();
        STAGE(1, 1, t + 2);            // overwrites B1(t); readers done pre-BAR
        MFMA_Q(1, 0, bf0);
    }

    // epilogue: D[reg r] = C[row=lq*4+r][col=lr]
    #pragma unroll
    for (int qb = 0; qb < 2; ++qb)
      #pragma unroll
      for (int in = 0; in < 2; ++in) {
        const int col = bn + qb * 128 + wc * 32 + in * 16 + lr;
        const float bc = bias[col];
        #pragma unroll
        for (int qa = 0; qa < 2; ++qa)
          #pragma unroll
          for (int im = 0; im < 4; ++im) {
            const int row0 = bm + qa * 128 + wr * 64 + im * 16 + lq * 4;
            #pragma unroll
            for (int r = 0; r < 4; ++r)
              Y[(size_t)(row0 + r) * N + col] = acc[qa][qb][im][in][r] + bc;
          }
      }
#undef STAGE
#undef LOAD_AF
#undef LOAD_BF
#undef MFMA_Q
}

// ---------------------------------------------------------------------------
// 128x128 fp16 GEMM (previous best) kept as shape fallback.
// ---------------------------------------------------------------------------
__global__ __launch_bounds__(256) void gemm_f16_lds(
    const _Float16* __restrict__ Xh,
    const _Float16* __restrict__ Wh,
    const float* __restrict__ bias,
    float* __restrict__ Y,
    int M, int N, int K)
{
    __shared__ _Float16 As[8192];
    __shared__ _Float16 Bs[8192];

    const int tid  = threadIdx.x;
    const int lane = tid & 63;
    const int w    = tid >> 6;
    const int lq   = lane >> 4;
    const int lr   = lane & 15;
    const int wy   = w >> 1;
    const int wx   = w & 1;
    const int l8   = lane >> 3;
    const int c8   = lane & 7;
    const int bm   = blockIdx.y * 128;
    const int bn   = blockIdx.x * 128;

    v4f acc[4][4];
    #pragma unroll
    for (int i = 0; i < 4; ++i)
        #pragma unroll
        for (int j = 0; j < 4; ++j)
            acc[i][j] = (v4f){0.f, 0.f, 0.f, 0.f};

    for (int k0 = 0; k0 < K; k0 += 64) {
        __syncthreads();
        #pragma unroll
        for (int ii = 0; ii < 4; ++ii) {
            const int chunk = w * 4 + ii;
            const int r     = chunk * 8 + l8;
            const int clog  = c8 ^ (r & 7);
            GLL16(Xh + (size_t)(bm + r) * K + k0 + clog * 8, As + chunk * 512);
            GLL16(Wh + (size_t)(bn + r) * K + k0 + clog * 8, Bs + chunk * 512);
        }
        __syncthreads();

        #pragma unroll
        for (int s = 0; s < 2; ++s) {
            v8h af[4], bf[4];
            #pragma unroll
            for (int im = 0; im < 4; ++im) {
                const int r  = wy * 64 + im * 16 + lr;
                const int cp = (s * 4 + lq) ^ (r & 7);
                af[im] = *(const v8h*)(As + r * 64 + cp * 8);
            }
            #pragma unroll
            for (int in = 0; in < 4; ++in) {
                const int r  = wx * 64 + in * 16 + lr;
                const int cp = (s * 4 + lq) ^ (r & 7);
                bf[in] = *(const v8h*)(Bs + r * 64 + cp * 8);
            }
            #pragma unroll
            for (int im = 0; im < 4; ++im)
                #pragma unroll
                for (int in = 0; in < 4; ++in)
                    acc[im][in] = __builtin_amdgcn_mfma_f32_16x16x32_f16(
                        af[im], bf[in], acc[im][in], 0, 0, 0);
        }
    }

    #pragma unroll
    for (int in = 0; in < 4; ++in) {
        const int col = bn + wx * 64 + in * 16 + lr;
        const float bc = bias[col];
        #pragma unroll
        for (int im = 0; im < 4; ++im) {
            const int row0 = bm + wy * 64 + im * 16 + lq * 4;
            #pragma unroll
            for (int r = 0; r < 4; ++r)
                Y[(size_t)(row0 + r) * N + col] = acc[im][in][r] + bc;
        }
    }
}

// ---------------------------------------------------------------------------
// Fallback GEMM (fp32 in, converts in-loop) if ws too small for fp16 copies.
// ---------------------------------------------------------------------------
#define BK 32
#define LDK 40
__global__ __launch_bounds__(256) void gemm_bias_f16(
    const float* __restrict__ X, const float* __restrict__ Wt,
    const float* __restrict__ bias, float* __restrict__ Y,
    int M, int N, int K)
{
    __shared__ _Float16 As[128 * LDK];
    __shared__ _Float16 Bs[128 * LDK];
    const int tid = threadIdx.x;
    const int lane = tid & 63, wave = tid >> 6;
    const int wy = wave >> 1, wx = wave & 1;
    const int lq = lane >> 4, lr = lane & 15;
    const int bm = blockIdx.y * 128, bn = blockIdx.x * 128;

    v4f acc[4][4];
    #pragma unroll
    for (int i = 0; i < 4; ++i)
        #pragma unroll
        for (int j = 0; j < 4; ++j)
            acc[i][j] = (v4f){0.f, 0.f, 0.f, 0.f};

    for (int k0 = 0; k0 < K; k0 += BK) {
        __syncthreads();
        #pragma unroll
        for (int j = 0; j < 4; ++j) {
            int flat = j * 1024 + tid * 4;
            int row = flat >> 5, col = flat & 31;
            float4 va = *(const float4*)(X  + (size_t)(bm + row) * K + k0 + col);
            float4 vb = *(const float4*)(Wt + (size_t)(bn + row) * K + k0 + col);
            v4h ha, hb;
            ha[0] = (_Float16)va.x; ha[1] = (_Float16)va.y;
            ha[2] = (_Float16)va.z; ha[3] = (_Float16)va.w;
            hb[0] = (_Float16)vb.x; hb[1] = (_Float16)vb.y;
            hb[2] = (_Float16)vb.z; hb[3] = (_Float16)vb.w;
            *(v4h*)(As + row * LDK + col) = ha;
            *(v4h*)(Bs + row * LDK + col) = hb;
        }
        __syncthreads();
        v8h af[4], bf[4];
        #pragma unroll
        for (int im = 0; im < 4; ++im)
            af[im] = *(const v8h*)(As + (wy * 64 + im * 16 + lr) * LDK + lq * 8);
        #pragma unroll
        for (int in = 0; in < 4; ++in)
            bf[in] = *(const v8h*)(Bs + (wx * 64 + in * 16 + lr) * LDK + lq * 8);
        #pragma unroll
        for (int im = 0; im < 4; ++im)
            #pragma unroll
            for (int in = 0; in < 4; ++in)
                acc[im][in] = __builtin_amdgcn_mfma_f32_16x16x32_f16(
                    af[im], bf[in], acc[im][in], 0, 0, 0);
    }
    #pragma unroll
    for (int in = 0; in < 4; ++in) {
        int col = bn + wx * 64 + in * 16 + lr;
        float bc = bias[col];
        #pragma unroll
        for (int im = 0; im < 4; ++im) {
            int row0 = bm + wy * 64 + im * 16 + lq * 4;
            #pragma unroll
            for (int r = 0; r < 4; ++r)
                Y[(size_t)(row0 + r) * N + col] = acc[im][in][r] + bc;
        }
    }
}

// ---------------------------------------------------------------------------
// FWHT -> quant -> FWHT, coalesced float4 global I/O.
// Phase ownership: P1 = bits {0,1,10,11}, P2 = bits {2..5}, P3 = bits {6..9}.
// LDS skew A(i) = i + 4*((i>>5)+(i>>8)) -> every phase <= 2-way / balanced.
// Quantizer: windowed searchsorted. i0 = clamp(floor(2.5z+7)-1, 0, 12) narrows
// the answer to {i0..i0+3}; 3 strict compares vs the REAL bp values (exact
// reference semantics; fp32 slop of 2.5z+7 is ~5e-6 vs the 1.0 window). The
// bp table is bank-replicated in LDS (bqs[j*32+c]) so lane L always reads
// bank L&31 -> 2-way, conflict-free.
// ---------------------------------------------------------------------------
#define LADDR(i) ((i) + 4 * (((i) >> 5) + ((i) >> 8)))

__device__ __forceinline__ void h4(float& a, float& b, float& c, float& d) {
    float t0 = a + b, t1 = a - b, t2 = c + d, t3 = c - d;
    a = t0 + t2; b = t1 + t3; c = t0 - t2; d = t1 - t3;
}

__device__ __forceinline__ void h16(float* v) {
    #pragma unroll
    for (int h = 1; h < 16; h <<= 1) {
        #pragma unroll
        for (int i = 0; i < 16; ++i) {
            if ((i & h) == 0) {
                float a = v[i], b = v[i + h];
                v[i] = a + b;
                v[i + h] = a - b;
            }
        }
    }
}

__global__ __launch_bounds__(256) void fwht_quant_fwht(
    float* __restrict__ Y, const float* __restrict__ flips,
    const float* __restrict__ bp)
{
    __shared__ float ld[4672];
    __shared__ float bqs[480];          // bqs[j*32 + c] = bp[j], j=0..14
    const int t = threadIdx.x;
    float* yrow = Y + (size_t)blockIdx.x * 4096;

    for (int i = t; i < 480; i += 256) bqs[i] = bp[i >> 5];
    const float* tb = bqs + (t & 31);   // this lane's bank-private copy

    float v[4][4];   // [j = bits 10,11][e = bits 0,1]
    #pragma unroll
    for (int j = 0; j < 4; ++j) {
        const int i = j * 1024 + t * 4;
        float4 xv = *(const float4*)(yrow + i);
        float4 fv = *(const float4*)(flips + i);
        v[j][0] = xv.x * fv.x; v[j][1] = xv.y * fv.y;
        v[j][2] = xv.z * fv.z; v[j][3] = xv.w * fv.w;
    }
    #pragma unroll
    for (int j = 0; j < 4; ++j) h4(v[j][0], v[j][1], v[j][2], v[j][3]); // h=1,2
    #pragma unroll
    for (int e = 0; e < 4; ++e) h4(v[0][e], v[1][e], v[2][e], v[3][e]); // h=1024,2048
    #pragma unroll
    for (int j = 0; j < 4; ++j)
        *(float4*)(ld + LADDR(j * 1024 + t * 4)) = *(float4*)&v[j][0];
    __syncthreads();

    float u[16];
    {   // P2: bits 2..5 (h = 4,8,16,32)
        const int base = (t & 3) + 64 * (t >> 2);
        #pragma unroll
        for (int m = 0; m < 16; ++m) u[m] = ld[LADDR(base + 4 * m)];
        h16(u);
        #pragma unroll
        for (int m = 0; m < 16; ++m) ld[LADDR(base + 4 * m)] = u[m];
    }
    __syncthreads();
    {   // P3: bits 6..9 (h = 64..512); FWHT#1 complete here -> quant -> FWHT#2
        const int base = (t & 63) + 1024 * (t >> 6);
        #pragma unroll
        for (int m = 0; m < 16; ++m) u[m] = ld[LADDR(base + 64 * m)];
        h16(u);
        #pragma unroll
        for (int m = 0; m < 16; ++m) {
            float z = u[m] * 0.015625f;
            float f = fmaf(z, 2.5f, 7.0f);
            int i0 = (int)floorf(f) - 1;
            i0 = i0 < 0 ? 0 : (i0 > 12 ? 12 : i0);
            const float* tb0 = tb + i0 * 32;
            int idx = i0 + (tb0[0] < z) + (tb0[32] < z) + (tb0[64] < z);
            u[m] = -3.0f + 0.4f * (float)idx;
        }
        h16(u);
        #pragma unroll
        for (int m = 0; m < 16; ++m) ld[LADDR(base + 64 * m)] = u[m];
    }
    __syncthreads();
    {   // P2' (h = 4..32)
        const int base = (t & 3) + 64 * (t >> 2);
        #pragma unroll
        for (int m = 0; m < 16; ++m) u[m] = ld[LADDR(base + 4 * m)];
        h16(u);
        #pragma unroll
        for (int m = 0; m < 16; ++m) ld[LADDR(base + 4 * m)] = u[m];
    }
    __syncthreads();
    // P1' (h = 1,2,1024,2048) + scale + flips + coalesced store
    #pragma unroll
    for (int j = 0; j < 4; ++j)
        *(float4*)&v[j][0] = *(const float4*)(ld + LADDR(j * 1024 + t * 4));
    #pragma unroll
    for (int j = 0; j < 4; ++j) h4(v[j][0], v[j][1], v[j][2], v[j][3]);
    #pragma unroll
    for (int e = 0; e < 4; ++e) h4(v[0][e], v[1][e], v[2][e], v[3][e]);
    #pragma unroll
    for (int j = 0; j < 4; ++j) {
        const int i = j * 1024 + t * 4;
        float4 fv = *(const float4*)(flips + i);
        float4 ov;
        ov.x = v[j][0] * 0.015625f * fv.x;
        ov.y = v[j][1] * 0.015625f * fv.y;
        ov.z = v[j][2] * 0.015625f * fv.z;
        ov.w = v[j][3] * 0.015625f * fv.w;
        *(float4*)(yrow + i) = ov;
    }
}

// ---------------------------------------------------------------------------
extern "C" void kernel_launch(void* const* d_in, const int* in_sizes, int n_in,
                              void* d_out, int out_size, void* d_ws, size_t ws_size,
                              hipStream_t stream) {
    const float* x     = (const float*)d_in[0];
    const float* W     = (const float*)d_in[1];
    const float* b     = (const float*)d_in[2];
    const float* flips = (const float*)d_in[3];
    const float* bp    = (const float*)d_in[4];
    float* out = (float*)d_out;

    const int N = in_sizes[2];            // 4096
    const int K = in_sizes[1] / N;        // 4096
    const int M = in_sizes[0] / K;        // 16384

    const size_t nX = (size_t)M * K;
    const size_t nW = (size_t)N * K;
    const size_t need = (nX + nW) * sizeof(_Float16);
    const bool big = (M % 256 == 0) && (N % 256 == 0) && (K % 64 == 0) && (K >= 128);

    if (ws_size >= need) {
        _Float16* Xh = (_Float16*)d_ws;
        _Float16* Wh = Xh + nX;
        cvt_f32_f16<<<(int)((nX + 2047) / 2048), 256, 0, stream>>>(x, Xh, nX);
        cvt_f32_f16<<<(int)((nW + 2047) / 2048), 256, 0, stream>>>(W, Wh, nW);
        if (big) {
            static bool attr_done = false;
            if (!attr_done) {
                hipFuncSetAttribute(reinterpret_cast<const void*>(gemm_f16_256),
                                    hipFuncAttributeMaxDynamicSharedMemorySize,
                                    131072);
                attr_done = true;
            }
            dim3 g((unsigned)((M / 256) * (N / 256)));
            gemm_f16_256<<<g, 512, 131072, stream>>>(Xh, Wh, b, out, M, N, K);
        } else {
            dim3 gg(N / 128, M / 128);
            gemm_f16_lds<<<gg, 256, 0, stream>>>(Xh, Wh, b, out, M, N, K);
        }
    } else {
        dim3 gg(N / 128, M / 128);
        gemm_bias_f16<<<gg, 256, 0, stream>>>(x, W, b, out, M, N, K);
    }
    fwht_quant_fwht<<<M, 256, 0, stream>>>(out, flips, bp);
}

// Round 3
// 1033.881 us; speedup vs baseline: 1.0460x; 1.0460x over previous
//
#include <hip/hip_runtime.h>
#include <stdint.h>

typedef _Float16 v8h __attribute__((ext_vector_type(8)));
typedef _Float16 v4h __attribute__((ext_vector_type(4)));
typedef float v4f __attribute__((ext_vector_type(4)));

#define GLL16(gp, lp) __builtin_amdgcn_global_load_lds( \
    (const __attribute__((address_space(1))) void*)(gp), \
    (__attribute__((address_space(3))) void*)(lp), 16, 0, 0)

// ---------------------------------------------------------------------------
// fp32 -> fp16 pack (8 elems/thread, coalesced)
// ---------------------------------------------------------------------------
__global__ __launch_bounds__(256) void cvt_f32_f16(
    const float* __restrict__ in, _Float16* __restrict__ out, size_t n)
{
    size_t i = ((size_t)blockIdx.x * 256 + threadIdx.x) * 8;
    if (i >= n) return;
    float4 a = *(const float4*)(in + i);
    float4 b = *(const float4*)(in + i + 4);
    v8h h;
    h[0] = (_Float16)a.x; h[1] = (_Float16)a.y;
    h[2] = (_Float16)a.z; h[3] = (_Float16)a.w;
    h[4] = (_Float16)b.x; h[5] = (_Float16)b.y;
    h[6] = (_Float16)b.z; h[7] = (_Float16)b.w;
    *(v8h*)(out + i) = h;
}

// ---------------------------------------------------------------------------
// 256x256-tile 8-wave GEMM, 4 phases/K-tile, 2 barriers/K-tile,
// PER-WAVE FRAGMENT READ-AHEAD: ds_reads for phase p+1 issue before phase p's
// MFMA cluster, so the DS pipe (≈2300 cyc/K-tile/CU) overlaps the MFMA pipe
// (≈2480 cyc/K-tile/CU) inside every wave instead of alternating.
//   Y[m,n] = sum_k Xh[m,k]*Wh[n,k] + bias[n]
// LDS (128 KiB dynamic): buf[2] x { A: 2 halves, B: 2 halves } of 128x64 fp16.
// Swizzle: physical 16B slot p of row r holds logical slot p ^ (r&7).
//
// Schedule per tile t (A-frag double set afA/afB; bf0,bf1 held across tile):
//  ph1: read bf0(t),bf1(t) | STAGE A1(t+1) | MFMA Q00(afA,bf0)
//       [afA(t) was pre-read at ph4(t-1); bf1 feeds ph2]
//  ph2: vmcnt(8) BAR | STAGE A0(t+2) | read afB<-A1(t) | MFMA Q01(afA,bf1)
//  ph3: STAGE B0(t+2) | MFMA Q11(afB,bf1)
//  ph4: vmcnt(6) BAR | STAGE B1(t+2) | pre-read afA<-A0(t+1) | MFMA Q10(afB,bf0)
// RAW: vmcnt(8)@ph2 forces A1(t) (5th-newest stage pair) landed before afB
//      reads; vmcnt(6)@ph4 forces A0/B0/B1(t+1) landed before ph4/ph1 reads.
// WAR: every region's last reads feed an MFMA that precedes the barrier
//      behind which the overwriting STAGE sits. vmcnt never drains to 0.
// ---------------------------------------------------------------------------
__global__ __launch_bounds__(512, 2) void gemm_f16_256(
    const _Float16* __restrict__ Xh,  // [M,K] fp16
    const _Float16* __restrict__ Wh,  // [N,K] fp16
    const float* __restrict__ bias,
    float* __restrict__ Y,
    int M, int N, int K)
{
    extern __shared__ _Float16 lds[];   // 65536 fp16 = 128 KiB
    const int NT   = K >> 6;            // K-tiles of 64
    const int tid  = threadIdx.x;
    const int lane = tid & 63;
    const int w    = tid >> 6;          // wave 0..7
    const int wr   = w >> 2;            // 0..1 (M sub-rows)
    const int wc   = w & 3;             // 0..3 (N sub-cols)
    const int lq   = lane >> 4;         // 0..3
    const int lr   = lane & 15;         // 0..15
    const int l8   = lane >> 3;         // 0..7
    const int c8   = lane & 7;          // 0..7
    const int lx   = lr & 7;

    // XCD-aware bijective block swizzle (grid is a multiple of 8 here)
    const int nwg = (int)gridDim.x;
    int wg = (int)blockIdx.x;
    if ((nwg & 7) == 0) wg = (wg & 7) * (nwg >> 3) + (wg >> 3);
    const int ntx = N >> 8;
    const int bx = wg % ntx, by = wg / ntx;
    const int bm = by << 8, bn = bx << 8;

    // staging invariants: per call a wave fills 8 rows x 64 fp16 (1 KiB linear)
    const int rbase = (w << 3) + l8;          // 0..63
    const int scol  = (c8 ^ l8) << 3;         // pre-swizzled source column
    const _Float16* pA = Xh + (size_t)(bm + rbase) * K + scol;
    const _Float16* pB = Wh + (size_t)(bn + rbase) * K + scol;

#define STAGE(mat, h, tt) do { \
    const int ttc = ((tt) < NT) ? (tt) : (NT - 1); \
    const _Float16* gp_ = (mat) ? pB : pA; \
    const size_t go_ = (size_t)((h) * 128) * K + (size_t)ttc * 64; \
    _Float16* lp_ = lds + (((tt) & 1) << 15) + ((mat) << 14) + ((h) << 13) + (w << 9); \
    GLL16(gp_ + go_, lp_); \
    GLL16(gp_ + go_ + (size_t)64 * K, lp_ + 4096); } while (0)

#define LOAD_AF(BUF, h, DST) do { \
    const _Float16* ab_ = lds + (BUF) + ((h) << 13); \
    _Pragma("unroll") \
    for (int im = 0; im < 4; ++im) { \
      const int rr_ = wr * 64 + im * 16 + lr; \
      _Pragma("unroll") \
      for (int ks = 0; ks < 2; ++ks) \
        DST[im][ks] = *(const v8h*)(ab_ + rr_ * 64 + (((ks * 4 + lq) ^ lx) << 3)); \
    } } while (0)

#define LOAD_BF(BUF, h, DST) do { \
    const _Float16* bb_ = lds + (BUF) + 16384 + ((h) << 13); \
    _Pragma("unroll") \
    for (int in = 0; in < 2; ++in) { \
      const int rr_ = wc * 32 + in * 16 + lr; \
      _Pragma("unroll") \
      for (int ks = 0; ks < 2; ++ks) \
        DST[in][ks] = *(const v8h*)(bb_ + rr_ * 64 + (((ks * 4 + lq) ^ lx) << 3)); \
    } } while (0)

#define MFMA_Q(qa, qb, AF, BF) do { \
    __builtin_amdgcn_s_setprio(1); \
    _Pragma("unroll") \
    for (int im = 0; im < 4; ++im) \
      _Pragma("unroll") \
      for (int in = 0; in < 2; ++in) \
        _Pragma("unroll") \
        for (int ks = 0; ks < 2; ++ks) \
          acc[qa][qb][im][in] = __builtin_amdgcn_mfma_f32_16x16x32_f16( \
              AF[im][ks], BF[in][ks], acc[qa][qb][im][in], 0, 0, 0); \
    __builtin_amdgcn_s_setprio(0); } while (0)

    v4f acc[2][2][4][2];
    #pragma unroll
    for (int qa = 0; qa < 2; ++qa)
      #pragma unroll
      for (int qb = 0; qb < 2; ++qb)
        #pragma unroll
        for (int im = 0; im < 4; ++im)
          #pragma unroll
          for (int in = 0; in < 2; ++in)
            acc[qa][qb][im][in] = (v4f){0.f, 0.f, 0.f, 0.f};

    v8h afA[4][2], afB[4][2], bf0[2][2], bf1[2][2];

    // prologue: 7 stages; vmcnt(8) leaves the newest 4 pairs in flight and
    // guarantees A0(0), B0(0), B1(0) landed. Pre-read afA for t=0.
    STAGE(0, 0, 0); STAGE(1, 0, 0); STAGE(1, 1, 0); STAGE(0, 1, 0);
    STAGE(0, 0, 1); STAGE(1, 0, 1); STAGE(1, 1, 1);
    asm volatile("s_waitcnt vmcnt(8)" ::: "memory");
    __builtin_amdgcn_s_barrier();
    LOAD_AF(0, 0, afA);                 // A0(0)

    for (int t = 0; t < NT; ++t) {
        const int cbuf = (t & 1) << 15;

        // ---- phase 1 : Q(A0,B0) ----
        LOAD_BF(cbuf, 0, bf0);          // B0(t): landed (vmcnt(6)@ph4(t-1))
        LOAD_BF(cbuf, 1, bf1);          // B1(t): landed; feeds ph2
        STAGE(0, 1, t + 1);             // A1(t+1) -> other buf
        MFMA_Q(0, 0, afA, bf0);

        // ---- phase 2 : Q(A0,B1) ----
        asm volatile("s_waitcnt vmcnt(8)" ::: "memory");  // A1(t) landed
        __builtin_amdgcn_s_barrier();
        STAGE(0, 0, t + 2);             // overwrites A0(t); last read ph4(t-1)
        LOAD_AF(cbuf, 1, afB);          // A1(t); feeds ph3/ph4, hides under Q01
        MFMA_Q(0, 1, afA, bf1);

        // ---- phase 3 : Q(A1,B1) ----  (no ds_reads; DS pipe drains afB)
        STAGE(1, 0, t + 2);             // overwrites B0(t); BAR@ph2 separates
        MFMA_Q(1, 1, afB, bf1);

        // ---- phase 4 : Q(A1,B0) ----
        asm volatile("s_waitcnt vmcnt(6)" ::: "memory");  // t+1's A0,B0,B1 landed
        __builtin_amdgcn_s_barrier();
        STAGE(1, 1, t + 2);             // overwrites B1(t); readers done pre-BAR
        LOAD_AF(cbuf ^ 32768, 0, afA);  // pre-read A0(t+1); hides under Q10
        MFMA_Q(1, 0, afB, bf0);
    }

    // epilogue: D[reg r] = C[row=lq*4+r][col=lr]
    #pragma unroll
    for (int qb = 0; qb < 2; ++qb)
      #pragma unroll
      for (int in = 0; in < 2; ++in) {
        const int col = bn + qb * 128 + wc * 32 + in * 16 + lr;
        const float bc = bias[col];
        #pragma unroll
        for (int qa = 0; qa < 2; ++qa)
          #pragma unroll
          for (int im = 0; im < 4; ++im) {
            const int row0 = bm + qa * 128 + wr * 64 + im * 16 + lq * 4;
            #pragma unroll
            for (int r = 0; r < 4; ++r)
              Y[(size_t)(row0 + r) * N + col] = acc[qa][qb][im][in][r] + bc;
          }
      }
#undef STAGE
#undef LOAD_AF
#undef LOAD_BF
#undef MFMA_Q
}

// ---------------------------------------------------------------------------
// 128x128 fp16 GEMM (previous best) kept as shape fallback.
// ---------------------------------------------------------------------------
__global__ __launch_bounds__(256) void gemm_f16_lds(
    const _Float16* __restrict__ Xh,
    const _Float16* __restrict__ Wh,
    const float* __restrict__ bias,
    float* __restrict__ Y,
    int M, int N, int K)
{
    __shared__ _Float16 As[8192];
    __shared__ _Float16 Bs[8192];

    const int tid  = threadIdx.x;
    const int lane = tid & 63;
    const int w    = tid >> 6;
    const int lq   = lane >> 4;
    const int lr   = lane & 15;
    const int wy   = w >> 1;
    const int wx   = w & 1;
    const int l8   = lane >> 3;
    const int c8   = lane & 7;
    const int bm   = blockIdx.y * 128;
    const int bn   = blockIdx.x * 128;

    v4f acc[4][4];
    #pragma unroll
    for (int i = 0; i < 4; ++i)
        #pragma unroll
        for (int j = 0; j < 4; ++j)
            acc[i][j] = (v4f){0.f, 0.f, 0.f, 0.f};

    for (int k0 = 0; k0 < K; k0 += 64) {
        __syncthreads();
        #pragma unroll
        for (int ii = 0; ii < 4; ++ii) {
            const int chunk = w * 4 + ii;
            const int r     = chunk * 8 + l8;
            const int clog  = c8 ^ (r & 7);
            GLL16(Xh + (size_t)(bm + r) * K + k0 + clog * 8, As + chunk * 512);
            GLL16(Wh + (size_t)(bn + r) * K + k0 + clog * 8, Bs + chunk * 512);
        }
        __syncthreads();

        #pragma unroll
        for (int s = 0; s < 2; ++s) {
            v8h af[4], bf[4];
            #pragma unroll
            for (int im = 0; im < 4; ++im) {
                const int r  = wy * 64 + im * 16 + lr;
                const int cp = (s * 4 + lq) ^ (r & 7);
                af[im] = *(const v8h*)(As + r * 64 + cp * 8);
            }
            #pragma unroll
            for (int in = 0; in < 4; ++in) {
                const int r  = wx * 64 + in * 16 + lr;
                const int cp = (s * 4 + lq) ^ (r & 7);
                bf[in] = *(const v8h*)(Bs + r * 64 + cp * 8);
            }
            #pragma unroll
            for (int im = 0; im < 4; ++im)
                #pragma unroll
                for (int in = 0; in < 4; ++in)
                    acc[im][in] = __builtin_amdgcn_mfma_f32_16x16x32_f16(
                        af[im], bf[in], acc[im][in], 0, 0, 0);
        }
    }

    #pragma unroll
    for (int in = 0; in < 4; ++in) {
        const int col = bn + wx * 64 + in * 16 + lr;
        const float bc = bias[col];
        #pragma unroll
        for (int im = 0; im < 4; ++im) {
            const int row0 = bm + wy * 64 + im * 16 + lq * 4;
            #pragma unroll
            for (int r = 0; r < 4; ++r)
                Y[(size_t)(row0 + r) * N + col] = acc[im][in][r] + bc;
        }
    }
}

// ---------------------------------------------------------------------------
// Fallback GEMM (fp32 in, converts in-loop) if ws too small for fp16 copies.
// ---------------------------------------------------------------------------
#define BK 32
#define LDK 40
__global__ __launch_bounds__(256) void gemm_bias_f16(
    const float* __restrict__ X, const float* __restrict__ Wt,
    const float* __restrict__ bias, float* __restrict__ Y,
    int M, int N, int K)
{
    __shared__ _Float16 As[128 * LDK];
    __shared__ _Float16 Bs[128 * LDK];
    const int tid = threadIdx.x;
    const int lane = tid & 63, wave = tid >> 6;
    const int wy = wave >> 1, wx = wave & 1;
    const int lq = lane >> 4, lr = lane & 15;
    const int bm = blockIdx.y * 128, bn = blockIdx.x * 128;

    v4f acc[4][4];
    #pragma unroll
    for (int i = 0; i < 4; ++i)
        #pragma unroll
        for (int j = 0; j < 4; ++j)
            acc[i][j] = (v4f){0.f, 0.f, 0.f, 0.f};

    for (int k0 = 0; k0 < K; k0 += BK) {
        __syncthreads();
        #pragma unroll
        for (int j = 0; j < 4; ++j) {
            int flat = j * 1024 + tid * 4;
            int row = flat >> 5, col = flat & 31;
            float4 va = *(const float4*)(X  + (size_t)(bm + row) * K + k0 + col);
            float4 vb = *(const float4*)(Wt + (size_t)(bn + row) * K + k0 + col);
            v4h ha, hb;
            ha[0] = (_Float16)va.x; ha[1] = (_Float16)va.y;
            ha[2] = (_Float16)va.z; ha[3] = (_Float16)va.w;
            hb[0] = (_Float16)vb.x; hb[1] = (_Float16)vb.y;
            hb[2] = (_Float16)vb.z; hb[3] = (_Float16)vb.w;
            *(v4h*)(As + row * LDK + col) = ha;
            *(v4h*)(Bs + row * LDK + col) = hb;
        }
        __syncthreads();
        v8h af[4], bf[4];
        #pragma unroll
        for (int im = 0; im < 4; ++im)
            af[im] = *(const v8h*)(As + (wy * 64 + im * 16 + lr) * LDK + lq * 8);
        #pragma unroll
        for (int in = 0; in < 4; ++in)
            bf[in] = *(const v8h*)(Bs + (wx * 64 + in * 16 + lr) * LDK + lq * 8);
        #pragma unroll
        for (int im = 0; im < 4; ++im)
            #pragma unroll
            for (int in = 0; in < 4; ++in)
                acc[im][in] = __builtin_amdgcn_mfma_f32_16x16x32_f16(
                    af[im], bf[in], acc[im][in], 0, 0, 0);
    }
    #pragma unroll
    for (int in = 0; in < 4; ++in) {
        int col = bn + wx * 64 + in * 16 + lr;
        float bc = bias[col];
        #pragma unroll
        for (int im = 0; im < 4; ++im) {
            int row0 = bm + wy * 64 + im * 16 + lq * 4;
            #pragma unroll
            for (int r = 0; r < 4; ++r)
                Y[(size_t)(row0 + r) * N + col] = acc[im][in][r] + bc;
        }
    }
}

// ---------------------------------------------------------------------------
// FWHT -> quant -> FWHT, coalesced float4 global I/O.
// Phase ownership: P1 = bits {0,1,10,11}, P2 = bits {2..5}, P3 = bits {6..9}.
// LDS skew A(i) = i + 4*((i>>5)+(i>>8)) -> every phase <= 2-way / balanced.
// Quantizer: windowed searchsorted vs real bp values (bit-exact w/ reference);
// bp table bank-replicated in LDS so every lane reads its own bank.
// ---------------------------------------------------------------------------
#define LADDR(i) ((i) + 4 * (((i) >> 5) + ((i) >> 8)))

__device__ __forceinline__ void h4(float& a, float& b, float& c, float& d) {
    float t0 = a + b, t1 = a - b, t2 = c + d, t3 = c - d;
    a = t0 + t2; b = t1 + t3; c = t0 - t2; d = t1 - t3;
}

__device__ __forceinline__ void h16(float* v) {
    #pragma unroll
    for (int h = 1; h < 16; h <<= 1) {
        #pragma unroll
        for (int i = 0; i < 16; ++i) {
            if ((i & h) == 0) {
                float a = v[i], b = v[i + h];
                v[i] = a + b;
                v[i + h] = a - b;
            }
        }
    }
}

__global__ __launch_bounds__(256) void fwht_quant_fwht(
    float* __restrict__ Y, const float* __restrict__ flips,
    const float* __restrict__ bp)
{
    __shared__ float ld[4672];
    __shared__ float bqs[480];          // bqs[j*32 + c] = bp[j], j=0..14
    const int t = threadIdx.x;
    float* yrow = Y + (size_t)blockIdx.x * 4096;

    for (int i = t; i < 480; i += 256) bqs[i] = bp[i >> 5];
    const float* tb = bqs + (t & 31);   // this lane's bank-private copy

    float v[4][4];   // [j = bits 10,11][e = bits 0,1]
    #pragma unroll
    for (int j = 0; j < 4; ++j) {
        const int i = j * 1024 + t * 4;
        float4 xv = *(const float4*)(yrow + i);
        float4 fv = *(const float4*)(flips + i);
        v[j][0] = xv.x * fv.x; v[j][1] = xv.y * fv.y;
        v[j][2] = xv.z * fv.z; v[j][3] = xv.w * fv.w;
    }
    #pragma unroll
    for (int j = 0; j < 4; ++j) h4(v[j][0], v[j][1], v[j][2], v[j][3]); // h=1,2
    #pragma unroll
    for (int e = 0; e < 4; ++e) h4(v[0][e], v[1][e], v[2][e], v[3][e]); // h=1024,2048
    #pragma unroll
    for (int j = 0; j < 4; ++j)
        *(float4*)(ld + LADDR(j * 1024 + t * 4)) = *(float4*)&v[j][0];
    __syncthreads();

    float u[16];
    {   // P2: bits 2..5 (h = 4,8,16,32)
        const int base = (t & 3) + 64 * (t >> 2);
        #pragma unroll
        for (int m = 0; m < 16; ++m) u[m] = ld[LADDR(base + 4 * m)];
        h16(u);
        #pragma unroll
        for (int m = 0; m < 16; ++m) ld[LADDR(base + 4 * m)] = u[m];
    }
    __syncthreads();
    {   // P3: bits 6..9 (h = 64..512); FWHT#1 complete here -> quant -> FWHT#2
        const int base = (t & 63) + 1024 * (t >> 6);
        #pragma unroll
        for (int m = 0; m < 16; ++m) u[m] = ld[LADDR(base + 64 * m)];
        h16(u);
        #pragma unroll
        for (int m = 0; m < 16; ++m) {
            float z = u[m] * 0.015625f;
            float f = fmaf(z, 2.5f, 7.0f);
            int i0 = (int)floorf(f) - 1;
            i0 = i0 < 0 ? 0 : (i0 > 12 ? 12 : i0);
            const float* tb0 = tb + i0 * 32;
            int idx = i0 + (tb0[0] < z) + (tb0[32] < z) + (tb0[64] < z);
            u[m] = -3.0f + 0.4f * (float)idx;
        }
        h16(u);
        #pragma unroll
        for (int m = 0; m < 16; ++m) ld[LADDR(base + 64 * m)] = u[m];
    }
    __syncthreads();
    {   // P2' (h = 4..32)
        const int base = (t & 3) + 64 * (t >> 2);
        #pragma unroll
        for (int m = 0; m < 16; ++m) u[m] = ld[LADDR(base + 4 * m)];
        h16(u);
        #pragma unroll
        for (int m = 0; m < 16; ++m) ld[LADDR(base + 4 * m)] = u[m];
    }
    __syncthreads();
    // P1' (h = 1,2,1024,2048) + scale + flips + coalesced store
    #pragma unroll
    for (int j = 0; j < 4; ++j)
        *(float4*)&v[j][0] = *(const float4*)(ld + LADDR(j * 1024 + t * 4));
    #pragma unroll
    for (int j = 0; j < 4; ++j) h4(v[j][0], v[j][1], v[j][2], v[j][3]);
    #pragma unroll
    for (int e = 0; e < 4; ++e) h4(v[0][e], v[1][e], v[2][e], v[3][e]);
    #pragma unroll
    for (int j = 0; j < 4; ++j) {
        const int i = j * 1024 + t * 4;
        float4 fv = *(const float4*)(flips + i);
        float4 ov;
        ov.x = v[j][0] * 0.015625f * fv.x;
        ov.y = v[j][1] * 0.015625f * fv.y;
        ov.z = v[j][2] * 0.015625f * fv.z;
        ov.w = v[j][3] * 0.015625f * fv.w;
        *(float4*)(yrow + i) = ov;
    }
}

// ---------------------------------------------------------------------------
extern "C" void kernel_launch(void* const* d_in, const int* in_sizes, int n_in,
                              void* d_out, int out_size, void* d_ws, size_t ws_size,
                              hipStream_t stream) {
    const float* x     = (const float*)d_in[0];
    const float* W     = (const float*)d_in[1];
    const float* b     = (const float*)d_in[2];
    const float* flips = (const float*)d_in[3];
    const float* bp    = (const float*)d_in[4];
    float* out = (float*)d_out;

    const int N = in_sizes[2];            // 4096
    const int K = in_sizes[1] / N;        // 4096
    const int M = in_sizes[0] / K;        // 16384

    const size_t nX = (size_t)M * K;
    const size_t nW = (size_t)N * K;
    const size_t need = (nX + nW) * sizeof(_Float16);
    const bool big = (M % 256 == 0) && (N % 256 == 0) && (K % 64 == 0) && (K >= 128);

    if (ws_size >= need) {
        _Float16* Xh = (_Float16*)d_ws;
        _Float16* Wh = Xh + nX;
        cvt_f32_f16<<<(int)((nX + 2047) / 2048), 256, 0, stream>>>(x, Xh, nX);
        cvt_f32_f16<<<(int)((nW + 2047) / 2048), 256, 0, stream>>>(W, Wh, nW);
        if (big) {
            static bool attr_done = false;
            if (!attr_done) {
                hipFuncSetAttribute(reinterpret_cast<const void*>(gemm_f16_256),
                                    hipFuncAttributeMaxDynamicSharedMemorySize,
                                    131072);
                attr_done = true;
            }
            dim3 g((unsigned)((M / 256) * (N / 256)));
            gemm_f16_256<<<g, 512, 131072, stream>>>(Xh, Wh, b, out, M, N, K);
        } else {
            dim3 gg(N / 128, M / 128);
            gemm_f16_lds<<<gg, 256, 0, stream>>>(Xh, Wh, b, out, M, N, K);
        }
    } else {
        dim3 gg(N / 128, M / 128);
        gemm_bias_f16<<<gg, 256, 0, stream>>>(x, W, b, out, M, N, K);
    }
    fwht_quant_fwht<<<M, 256, 0, stream>>>(out, flips, bp);
}